// Round 13
// baseline (31.181 us; speedup 1.0000x reference)
//
#include <hip/hip_runtime.h>
#include <cstdint>
#include <cstddef>

#define SIGMA_INV 10.0f
#define EPS_C 1e-7f

constexpr int TDIM = 512;   // time bins
constexpr int ROWS2 = 8;    // rows per block (K1): 1 row per wave
constexpr int PITCH = 513;  // LDS pitch (f32), conflict-free column reads
constexpr int NB1 = 1024;   // K1 grid = N/ROWS2
constexpr int NB2 = 512;    // K2 grid = TDIM
constexpr int MAXC = 256;   // max bucket size (actual ~16, tail ~45)
constexpr int GSTRIDE = 32; // 128 B / 4 B: one counter line per bucket/group

// Ledger (R5-R12): fixed per-replay overhead ~15us (kernel count nearly free:
// R10 3-kernel 23.6 vs R12 2-kernel 23.9); 512 RMWs on ONE line ~4.5us (R9);
// sc1 write-through stores cheap, sc1 BULK loads expensive (R8); in-kernel
// grid barriers always lose to the kernel boundary (R5-R8,R11). This round
// attacks the ~8us of actual kernel work: K2's kidx scan is replaced by
// K1-built per-bucket member lists on 128B-padded hist lines.
__device__ __forceinline__ void stf(float* p, float v) {
    __hip_atomic_store(p, v, __ATOMIC_RELAXED, __HIP_MEMORY_SCOPE_AGENT);
}
__device__ __forceinline__ void sti(int* p, int v) {
    __hip_atomic_store(p, v, __ATOMIC_RELAXED, __HIP_MEMORY_SCOPE_AGENT);
}
__device__ __forceinline__ float ldf(const float* p) {
    return __hip_atomic_load(p, __ATOMIC_RELAXED, __HIP_MEMORY_SCOPE_AGENT);
}
__device__ __forceinline__ int ldi(const int* p) {
    return __hip_atomic_load(p, __ATOMIC_RELAXED, __HIP_MEMORY_SCOPE_AGENT);
}

// K1: per-row cumsum (tree scan, 1 row/wave); nll/scale/einv; per-block SGTp
// partials; per-bucket member lists via padded-line atomics. Normal stores —
// the K1->K2 kernel boundary publishes everything.
__global__ __launch_bounds__(512, 4) void rows_kernel(
    const float* __restrict__ pmf, const float* __restrict__ times,
    const int* __restrict__ events, const float* __restrict__ bins,
    unsigned* __restrict__ hist,      // 512 x 128B lines: bucket counts
    int* __restrict__ member,        // [512][MAXC] member row indices
    float* __restrict__ SGTp, float* __restrict__ scaleA,
    float* __restrict__ einvA,
    float* __restrict__ nll_part, int* __restrict__ ev_part, int N)
{
    __shared__ float tile[ROWS2 * PITCH];   // 16,416 B
    __shared__ float binsS[TDIM];
    __shared__ int karr[ROWS2];
    __shared__ float nllv[ROWS2];
    __shared__ int evv[ROWS2];
    const int tid = threadIdx.x;
    const int lane = tid & 63;
    const int wid = tid >> 6;            // 8 waves, 1 row each
    const int b = blockIdx.x;
    const int i0 = b * ROWS2;

    binsS[tid] = bins[tid];              // TDIM == blockDim == 512

    // One row per wave: load 8 f32, local prefix, 6-step shfl scan.
    {
        const int i = i0 + wid;
        const float4* p4 = (const float4*)(pmf + (size_t)i * TDIM + lane * 8);
        const float4 a = p4[0];
        const float4 bq = p4[1];
        float c0 = a.x, c1 = c0 + a.y, c2 = c1 + a.z, c3 = c2 + a.w;
        float c4 = c3 + bq.x, c5 = c4 + bq.y, c6 = c5 + bq.z, c7 = c6 + bq.w;
        float v = c7;
        #pragma unroll
        for (int d = 1; d < 64; d <<= 1) {
            float u = __shfl_up(v, d);
            if (lane >= d) v += u;
        }
        const float excl = v - c7;           // exclusive prefix of lane sums
        float* t = tile + wid * PITCH + lane * 8;
        t[0] = c0 + excl; t[1] = c1 + excl; t[2] = c2 + excl; t[3] = c3 + excl;
        t[4] = c4 + excl; t[5] = c5 + excl; t[6] = c6 + excl; t[7] = c7 + excl;
    }
    __syncthreads();

    if (tid < ROWS2) {
        const int i = i0 + tid;
        const float t = times[i];
        // searchsorted(bins, t, side='left') on LDS-cached bins
        int lo = 0, hi = TDIM;
        while (lo < hi) {
            int mid = (lo + hi) >> 1;
            if (binsS[mid] < t) lo = mid + 1; else hi = mid;
        }
        int k = lo - 1;
        k = k < 0 ? 0 : (k > TDIM - 1 ? TDIM - 1 : k);
        const float cdf_at = tile[tid * PITCH + k];
        const float tot = tile[tid * PITCH + (TDIM - 1)];
        const float pmf_at = pmf[(size_t)i * TDIM + k];
        const float surv = tot - cdf_at + pmf_at;
        nllv[tid] = (events[i] == 1) ? -logf(pmf_at + EPS_C) : -logf(surv + EPS_C);
        evv[tid] = events[i];
        scaleA[i] = expf(-cdf_at * SIGMA_INV);
        einvA[i] = expf(cdf_at * SIGMA_INV);
        karr[tid] = k;
        // Member list: ~16 RMWs per 128B hist line across the whole grid —
        // parallel across 512 lines (R9 lesson: never pile RMWs on one line).
        const unsigned slot = atomicAdd(&hist[k * GSTRIDE], 1u);
        if (slot < (unsigned)MAXC) member[k * MAXC + slot] = i;
    }
    __syncthreads();

    // Column-owner accumulation: k = tid, 8 rows, deterministic order.
    float acc = 0.f;
    #pragma unroll
    for (int s = 0; s < ROWS2; ++s) {
        const float c = tile[s * PITCH + tid];
        if (tid < karr[s]) acc += expf(c * SIGMA_INV);
    }
    SGTp[(size_t)b * TDIM + tid] = acc;   // coalesced

    if (wid == 0) {
        float nv = (lane < ROWS2) ? nllv[lane] : 0.f;
        int ev = (lane < ROWS2) ? evv[lane] : 0;
        #pragma unroll
        for (int d = 4; d > 0; d >>= 1) {
            nv += __shfl_down(nv, d);
            ev += __shfl_down(ev, d);
        }
        if (lane == 0) { nll_part[b] = nv; ev_part[b] = ev; }
    }
}

// K2: block k reduces SGTp[:,k]; C_GT from hist suffix; members from list
// (no kidx scan); exact in-bucket correction; publishes rank/npair (sc1);
// two-level ticket; global-last block combines and writes the scalar.
__global__ __launch_bounds__(512, 4) void bucket_final_kernel(
    const float* __restrict__ SGTp, const float* __restrict__ times,
    const int* __restrict__ events,
    const float* __restrict__ scaleA, const float* __restrict__ einvA,
    const float* __restrict__ nll_part, const int* __restrict__ ev_part,
    const unsigned* __restrict__ hist, const int* __restrict__ member,
    unsigned* __restrict__ tkt,
    float* __restrict__ rank_part, int* __restrict__ npair_part,
    float* __restrict__ out, int N)
{
    __shared__ float redf[8];
    __shared__ int redi[8];
    __shared__ float red2f[8];
    __shared__ int red2i[8];
    __shared__ int cj[MAXC], oj[MAXC];
    __shared__ float mt[MAXC], me[MAXC];
    __shared__ int nc_sh;
    __shared__ float SGT_sh;
    __shared__ int CGT_sh;
    __shared__ int last_sh;
    __shared__ double sd1[NB2];
    __shared__ double sd2[NB2];
    __shared__ int si1[NB2];
    __shared__ int si2[NB2];

    const int k = blockIdx.x;
    const int tid = threadIdx.x;
    const int lane = tid & 63;
    const int wid = tid >> 6;

    // SGT[k] = sum over 1024 K1-blocks (fixed pairing -> deterministic).
    float sv = SGTp[(size_t)tid * TDIM + k] + SGTp[(size_t)(tid + 512) * TDIM + k];
    #pragma unroll
    for (int d = 32; d > 0; d >>= 1) sv += __shfl_down(sv, d);
    if (lane == 0) redf[wid] = sv;

    // C_GT[k] = sum_{m>k} hist[m]: thread tid owns bin tid.
    const unsigned h = hist[tid * GSTRIDE];
    int cnt = (tid > k) ? (int)h : 0;
    #pragma unroll
    for (int d = 32; d > 0; d >>= 1) cnt += __shfl_down(cnt, d);
    if (lane == 0) redi[wid] = cnt;
    __syncthreads();
    if (tid == 0) {
        float s8 = 0.f; int c8 = 0;
        #pragma unroll
        for (int w = 0; w < 8; ++w) { s8 += redf[w]; c8 += redi[w]; }
        SGT_sh = s8; CGT_sh = c8;
        const unsigned hk = hist[k * GSTRIDE];
        nc_sh = hk < (unsigned)MAXC ? (int)hk : MAXC;
    }
    __syncthreads();

    const int nc = nc_sh;
    if (tid < nc) cj[tid] = member[k * MAXC + tid];
    __syncthreads();
    // Rank-reorder members by j (deterministic despite atomic collection).
    if (tid < nc) {
        const int myj = cj[tid];
        int r = 0;
        for (int m = 0; m < nc; ++m) r += (cj[m] < myj) ? 1 : 0;
        oj[r] = myj;
    }
    __syncthreads();
    if (tid < nc) { mt[tid] = times[oj[tid]]; me[tid] = einvA[oj[tid]]; }
    __syncthreads();

    float pi = 0.f;
    int vf = 0;
    if (tid < nc) {
        const int i = oj[tid];
        const float ti = mt[tid];
        float s = 0.f;
        int c = 0;
        for (int m = 0; m < nc; ++m) {
            if (mt[m] > ti) { s += me[m]; c++; }
        }
        const int C = CGT_sh + c;
        if (events[i] == 1 && C > 0) {
            vf = 1;
            pi = scaleA[i] * (SGT_sh + s) / (float)C;
        }
    }
    #pragma unroll
    for (int d = 32; d > 0; d >>= 1) {
        pi += __shfl_down(pi, d);
        vf += __shfl_down(vf, d);
    }
    if (lane == 0) { red2f[wid] = pi; red2i[wid] = vf; }
    __syncthreads();
    if (tid == 0) {
        float s8 = 0.f; int c8 = 0;
        #pragma unroll
        for (int w = 0; w < 8; ++w) { s8 += red2f[w]; c8 += red2i[w]; }
        stf(rank_part + k, s8);      // sc1 write-through: visible at LLC
        sti(npair_part + k, c8);
    }

    // Two-level ticket: line (k&63) takes 8 RMWs (parallel across 64 lines);
    // each line's 8th arriver bumps lvl2 (64 RMWs); lvl2's 64th is last.
    __syncthreads();
    if (tid == 0) {
        asm volatile("s_waitcnt vmcnt(0)" ::: "memory");
        int is_last = 0;
        unsigned g = __hip_atomic_fetch_add(tkt + (k & 63) * GSTRIDE, 1u,
                                            __ATOMIC_RELAXED,
                                            __HIP_MEMORY_SCOPE_AGENT);
        if (g == 7u) {
            unsigned l2 = __hip_atomic_fetch_add(tkt + 64 * GSTRIDE, 1u,
                                                 __ATOMIC_RELAXED,
                                                 __HIP_MEMORY_SCOPE_AGENT);
            if (l2 == 63u) is_last = 1;
        }
        last_sh = is_last;
    }
    __syncthreads();
    if (!last_sh) return;

    // Global-last block: combine 1024 nll/ev + 512 rank/npair partials.
    sd1[tid] = (double)nll_part[tid] + (double)nll_part[tid + 512];
    si2[tid] = ev_part[tid] + ev_part[tid + 512];
    sd2[tid] = (double)ldf(rank_part + tid);   // K2 peers: sc1 loads
    si1[tid] = ldi(npair_part + tid);
    __syncthreads();
    for (int off = 256; off > 0; off >>= 1) {
        if (tid < off) {
            sd1[tid] += sd1[tid + off];
            sd2[tid] += sd2[tid + off];
            si1[tid] += si1[tid + off];
            si2[tid] += si2[tid + off];
        }
        __syncthreads();
    }
    if (tid == 0) {
        double loss = sd1[0] / (double)N;
        if (si2[0] > 1 && si1[0] > 0) loss += 0.5 * sd2[0] / (double)si1[0];
        out[0] = (float)loss;
    }
}

extern "C" void kernel_launch(void* const* d_in, const int* in_sizes, int n_in,
                              void* d_out, int out_size, void* d_ws, size_t ws_size,
                              hipStream_t stream) {
    const float* pmf = (const float*)d_in[0];
    const float* times = (const float*)d_in[1];
    const int* events = (const int*)d_in[2];
    const float* bins = (const float*)d_in[3];
    const int N = in_sizes[1];  // 8192

    char* ws = (char*)d_ws;
    unsigned* tkt = (unsigned*)ws;                       // 65 x 128 B lines
    unsigned* hist = (unsigned*)(ws + 65 * 128);         // 512 x 128 B lines
    int* member = (int*)(ws + (65 + 512) * 128);         // 512 * MAXC ints
    float* SGTp = (float*)(ws + (65 + 512) * 128 + 512 * MAXC * 4);  // NB1*TDIM
    float* scaleA = SGTp + (size_t)NB1 * TDIM;           // N
    float* einvA = scaleA + N;                           // N
    float* nll_part = einvA + N;                         // NB1
    float* rank_part = nll_part + NB1;                   // NB2
    int* ev_part = (int*)(rank_part + NB2);              // NB1
    int* npair_part = ev_part + NB1;                     // NB2

    hipMemsetAsync(ws, 0, (65 + 512) * 128, stream);     // tkt + hist
    rows_kernel<<<NB1, 512, 0, stream>>>(
        pmf, times, events, bins, hist, member, SGTp, scaleA, einvA,
        nll_part, ev_part, N);
    bucket_final_kernel<<<NB2, 512, 0, stream>>>(
        SGTp, times, events, scaleA, einvA, nll_part, ev_part,
        hist, member, tkt, rank_part, npair_part, (float*)d_out, N);
}

// Round 14
// 23.623 us; speedup vs baseline: 1.3199x; 1.3199x over previous
//
#include <hip/hip_runtime.h>
#include <cstdint>
#include <cstddef>

#define SIGMA_INV 10.0f
#define EPS_C 1e-7f

constexpr int TDIM = 512;   // time bins
constexpr int ROWS2 = 16;   // rows per block (K1)
constexpr int PITCH = 513;  // LDS pitch (f32), conflict-free column reads
constexpr int NBLK = 512;   // K1/K2 grid = N/ROWS2 = TDIM
constexpr int MAXC = 256;   // max bucket size (actual ~16)

// Final structure (measured optimum, R10 = 23.6us):
//  * 3 kernels, kernel-boundary sync only, ZERO global atomics, no memset.
//  * Ledger: fixed per-replay overhead ~15us; kernel work ~8us; every extra
//    graph node / in-kernel convergence structure costs MORE than it saves
//    (R11 fused barrier +5us, R12 in-kernel ticket +0.3us, R13 list-build
//    +7.5us, R9 single-line 512-RMW ticket +4.5us, R5-R8 barriers +20-45us).

// K1: per-row cumsum (tree scan) into LDS tile; nll/scale/einv/kidx; per-block
// partial SGTp[b][k]. Thread tid owns column k=tid -> register accumulator.
__global__ __launch_bounds__(512, 4) void rows_kernel(
    const float* __restrict__ pmf, const float* __restrict__ times,
    const int* __restrict__ events, const float* __restrict__ bins,
    float* __restrict__ SGTp, float* __restrict__ scaleA,
    float* __restrict__ einvA, int* __restrict__ kidxA,
    float* __restrict__ nll_part, int* __restrict__ ev_part, int N)
{
    __shared__ float tile[ROWS2 * PITCH];   // 32,832 B
    __shared__ float binsS[TDIM];
    __shared__ int karr[ROWS2];
    __shared__ float nllv[ROWS2];
    __shared__ int evv[ROWS2];
    const int tid = threadIdx.x;
    const int lane = tid & 63;
    const int wid = tid >> 6;            // 8 waves, 2 rows each
    const int b = blockIdx.x;
    const int i0 = b * ROWS2;

    binsS[tid] = bins[tid];              // TDIM == blockDim == 512

    float4 A[2][2];
    #pragma unroll
    for (int r = 0; r < 2; ++r) {
        const int i = i0 + wid * 2 + r;
        const float4* p4 = (const float4*)(pmf + (size_t)i * TDIM + lane * 8);
        A[r][0] = p4[0];
        A[r][1] = p4[1];
    }
    #pragma unroll
    for (int r = 0; r < 2; ++r) {
        const int rl = wid * 2 + r;
        float c0 = A[r][0].x, c1 = c0 + A[r][0].y, c2 = c1 + A[r][0].z, c3 = c2 + A[r][0].w;
        float c4 = c3 + A[r][1].x, c5 = c4 + A[r][1].y, c6 = c5 + A[r][1].z, c7 = c6 + A[r][1].w;
        float v = c7;
        #pragma unroll
        for (int d = 1; d < 64; d <<= 1) {
            float u = __shfl_up(v, d);
            if (lane >= d) v += u;
        }
        const float excl = v - c7;           // exclusive prefix of lane sums
        float* t = tile + rl * PITCH + lane * 8;
        t[0] = c0 + excl; t[1] = c1 + excl; t[2] = c2 + excl; t[3] = c3 + excl;
        t[4] = c4 + excl; t[5] = c5 + excl; t[6] = c6 + excl; t[7] = c7 + excl;
    }
    __syncthreads();

    if (tid < ROWS2) {
        const int i = i0 + tid;
        const float t = times[i];
        // searchsorted(bins, t, side='left') on LDS-cached bins
        int lo = 0, hi = TDIM;
        while (lo < hi) {
            int mid = (lo + hi) >> 1;
            if (binsS[mid] < t) lo = mid + 1; else hi = mid;
        }
        int k = lo - 1;
        k = k < 0 ? 0 : (k > TDIM - 1 ? TDIM - 1 : k);
        const float cdf_at = tile[tid * PITCH + k];
        const float tot = tile[tid * PITCH + (TDIM - 1)];
        const float pmf_at = pmf[(size_t)i * TDIM + k];
        const float surv = tot - cdf_at + pmf_at;
        nllv[tid] = (events[i] == 1) ? -logf(pmf_at + EPS_C) : -logf(surv + EPS_C);
        evv[tid] = events[i];
        scaleA[i] = expf(-cdf_at * SIGMA_INV);
        einvA[i] = expf(cdf_at * SIGMA_INV);
        kidxA[i] = k;
        karr[tid] = k;
    }
    __syncthreads();

    // Column-owner accumulation: k = tid, 16 rows, deterministic order.
    float acc = 0.f;
    #pragma unroll
    for (int s = 0; s < ROWS2; ++s) {
        const float c = tile[s * PITCH + tid];
        if (tid < karr[s]) acc += expf(c * SIGMA_INV);
    }
    SGTp[(size_t)b * TDIM + tid] = acc;   // coalesced

    if (wid == 0) {
        float nv = (lane < ROWS2) ? nllv[lane] : 0.f;
        int ev = (lane < ROWS2) ? evv[lane] : 0;
        #pragma unroll
        for (int d = 8; d > 0; d >>= 1) {
            nv += __shfl_down(nv, d);
            ev += __shfl_down(ev, d);
        }
        if (lane == 0) { nll_part[b] = nv; ev_part[b] = ev; }
    }
}

// K2: block k reduces SGTp[:,k] (L2-cached), scans kidx (int4, L2), exact
// in-bucket correction, writes rank/npair partials with NORMAL stores.
__global__ __launch_bounds__(512, 4) void bucket_kernel(
    const float* __restrict__ SGTp, const float* __restrict__ times,
    const int* __restrict__ events, const int* __restrict__ kidxA,
    const float* __restrict__ scaleA, const float* __restrict__ einvA,
    float* __restrict__ rank_part, int* __restrict__ npair_part, int N)
{
    __shared__ float redf[8];
    __shared__ int redi[8];
    __shared__ float red2f[8];
    __shared__ int red2i[8];
    __shared__ int cj[MAXC], oj[MAXC];
    __shared__ float mt[MAXC], me[MAXC];
    __shared__ int ncl_sh;
    __shared__ float SGT_sh;
    __shared__ int CGT_sh;

    const int k = blockIdx.x;
    const int tid = threadIdx.x;
    const int lane = tid & 63;
    const int wid = tid >> 6;

    if (tid == 0) ncl_sh = 0;
    __syncthreads();

    // SGT[k] = sum_b SGTp[b][k]; thread tid handles b = tid (NBLK == 512).
    float sv = SGTp[(size_t)tid * TDIM + k];
    #pragma unroll
    for (int d = 32; d > 0; d >>= 1) sv += __shfl_down(sv, d);
    if (lane == 0) redf[wid] = sv;

    int cnt = 0;
    const int4* kx4 = (const int4*)kidxA;
    #pragma unroll
    for (int it = 0; it < 4; ++it) {
        const int ch = it * 512 + tid;      // N/4 == 2048 chunks
        const int4 kx = kx4[ch];
        const int j0 = ch * 4;
        cnt += (kx.x > k) + (kx.y > k) + (kx.z > k) + (kx.w > k);
        if (kx.x == k) { int p = atomicAdd(&ncl_sh, 1); if (p < MAXC) cj[p] = j0 + 0; }
        if (kx.y == k) { int p = atomicAdd(&ncl_sh, 1); if (p < MAXC) cj[p] = j0 + 1; }
        if (kx.z == k) { int p = atomicAdd(&ncl_sh, 1); if (p < MAXC) cj[p] = j0 + 2; }
        if (kx.w == k) { int p = atomicAdd(&ncl_sh, 1); if (p < MAXC) cj[p] = j0 + 3; }
    }
    #pragma unroll
    for (int d = 32; d > 0; d >>= 1) cnt += __shfl_down(cnt, d);
    if (lane == 0) redi[wid] = cnt;
    __syncthreads();
    if (tid == 0) {
        float s8 = 0.f; int c8 = 0;
        #pragma unroll
        for (int w = 0; w < 8; ++w) { s8 += redf[w]; c8 += redi[w]; }
        SGT_sh = s8; CGT_sh = c8;
    }
    __syncthreads();

    const int nc = ncl_sh < MAXC ? ncl_sh : MAXC;
    // Rank-reorder members by j (deterministic despite atomic collection).
    if (tid < nc) {
        const int myj = cj[tid];
        int r = 0;
        for (int m = 0; m < nc; ++m) r += (cj[m] < myj) ? 1 : 0;
        oj[r] = myj;
    }
    __syncthreads();
    if (tid < nc) { mt[tid] = times[oj[tid]]; me[tid] = einvA[oj[tid]]; }
    __syncthreads();

    float pi = 0.f;
    int vf = 0;
    if (tid < nc) {
        const int i = oj[tid];
        const float ti = mt[tid];
        float s = 0.f;
        int c = 0;
        for (int m = 0; m < nc; ++m) {
            if (mt[m] > ti) { s += me[m]; c++; }
        }
        const int C = CGT_sh + c;
        if (events[i] == 1 && C > 0) {
            vf = 1;
            pi = scaleA[i] * (SGT_sh + s) / (float)C;
        }
    }
    #pragma unroll
    for (int d = 32; d > 0; d >>= 1) {
        pi += __shfl_down(pi, d);
        vf += __shfl_down(vf, d);
    }
    if (lane == 0) { red2f[wid] = pi; red2i[wid] = vf; }
    __syncthreads();
    if (tid == 0) {
        float s8 = 0.f; int c8 = 0;
        #pragma unroll
        for (int w = 0; w < 8; ++w) { s8 += red2f[w]; c8 += red2i[w]; }
        rank_part[k] = s8;
        npair_part[k] = c8;
    }
}

// K3: combine 512-entry partial arrays in double; write scalar loss.
__global__ __launch_bounds__(512) void final_kernel(
    const float* __restrict__ nll_part, const int* __restrict__ ev_part,
    const float* __restrict__ rank_part, const int* __restrict__ npair_part,
    float* __restrict__ out, int N)
{
    __shared__ double sd1[NBLK];
    __shared__ double sd2[NBLK];
    __shared__ int si1[NBLK];
    __shared__ int si2[NBLK];
    const int t = threadIdx.x;
    sd1[t] = (double)nll_part[t];
    sd2[t] = (double)rank_part[t];
    si1[t] = npair_part[t];
    si2[t] = ev_part[t];
    __syncthreads();
    for (int off = 256; off > 0; off >>= 1) {
        if (t < off) {
            sd1[t] += sd1[t + off];
            sd2[t] += sd2[t + off];
            si1[t] += si1[t + off];
            si2[t] += si2[t + off];
        }
        __syncthreads();
    }
    if (t == 0) {
        double loss = sd1[0] / (double)N;
        if (si2[0] > 1 && si1[0] > 0) loss += 0.5 * sd2[0] / (double)si1[0];
        out[0] = (float)loss;
    }
}

extern "C" void kernel_launch(void* const* d_in, const int* in_sizes, int n_in,
                              void* d_out, int out_size, void* d_ws, size_t ws_size,
                              hipStream_t stream) {
    const float* pmf = (const float*)d_in[0];
    const float* times = (const float*)d_in[1];
    const int* events = (const int*)d_in[2];
    const float* bins = (const float*)d_in[3];
    const int N = in_sizes[1];  // 8192

    char* ws = (char*)d_ws;
    float* SGTp = (float*)(ws + 256);                    // NBLK * TDIM
    float* scaleA = SGTp + (size_t)NBLK * TDIM;          // N
    float* einvA = scaleA + N;                           // N
    float* nll_part = einvA + N;                         // NBLK
    float* rank_part = nll_part + NBLK;                  // TDIM
    int* kidxA = (int*)(rank_part + TDIM);               // N
    int* ev_part = kidxA + N;                            // NBLK
    int* npair_part = ev_part + NBLK;                    // TDIM

    rows_kernel<<<NBLK, 512, 0, stream>>>(
        pmf, times, events, bins, SGTp, scaleA, einvA, kidxA,
        nll_part, ev_part, N);
    bucket_kernel<<<NBLK, 512, 0, stream>>>(
        SGTp, times, events, kidxA, scaleA, einvA,
        rank_part, npair_part, N);
    final_kernel<<<1, 512, 0, stream>>>(
        nll_part, ev_part, rank_part, npair_part, (float*)d_out, N);
}